// Round 9
// baseline (633.841 us; speedup 1.0000x reference)
//
#include <hip/hip_runtime.h>
#include <hip/hip_bf16.h>

// NNConv GNN, round 16: kill the two measured serializers.
//  R15 post-mortem: (a) ugemm restaged B (278 KB K2q) into LDS every chunk
//  from every block = 174 MB/dispatch of L2->LDS traffic, all drained to
//  vmcnt(0) at each barrier -> staging drain was the chunk critical path.
//  (b) ucomp's eks/smeta loads use readfirstlane -> SCALAR (K$) path; the
//  scalar cache's few MSHRs x ~900cy HBM misses x 256 CU ~= 35 us — matches
//  ucomp's ~33 us exactly. Wave TLP can't hide a scalar-pipe MSHR limit.
//  R16: (1) ucomp forces eks/smeta onto the vector (TCP) path via an opaque
//  v_mov (VGPR-typed index -> global_load_dwordx4, same-address broadcast).
//  (2) ugemm stages ONLY A (4 KB/chunk dbuf, 16-row tile, 1250 blocks all
//  resident, 4 waves); B read straight from L2-hot K2q inside the loop,
//  hidden by ~20 waves/CU TLP. MFMA order unchanged -> bitwise-same result.

#define NN 20000
#define NE 100000
#define WD 64
#define DEPTH 6

typedef __attribute__((ext_vector_type(8))) short bf16x8;
typedef __attribute__((ext_vector_type(4))) float f32x4;

typedef __attribute__((address_space(1))) const void gvoid;
typedef __attribute__((address_space(3))) void lvoid;
__device__ __forceinline__ void gl_lds16(const void* g, void* l) {
    __builtin_amdgcn_global_load_lds((gvoid*)g, (lvoid*)l, 16, 0, 0);
}
// opaque SGPR->VGPR move: forces subsequent address math onto the vector
// memory path (TCP) instead of the scalar K$ path.
__device__ __forceinline__ int to_vgpr(int s) {
    int v; asm("v_mov_b32 %0, %1" : "=v"(v) : "s"(s)); return v;
}

__device__ __forceinline__ unsigned short f2bf(float v) {
    union { float f; unsigned u; } x; x.f = v;
    unsigned r = x.u + 0x7fffu + ((x.u >> 16) & 1u);
    return (unsigned short)(r >> 16);
}
__device__ __forceinline__ float bf2f(unsigned short b) {
    union { unsigned u; float f; } x; x.u = ((unsigned)b) << 16;
    return x.f;
}

// ---------------- per-node in/out degree counts ----------------
__global__ __launch_bounds__(256) void count_kernel(const int* __restrict__ ei,
                                                    int* __restrict__ outc,
                                                    int* __restrict__ inc)
{
    int e = blockIdx.x * 256 + threadIdx.x;
    if (e >= NE) return;
    atomicAdd(&outc[ei[e]], 1);
    atomicAdd(&inc[ei[NE + e]], 1);
}

// ---------------- hierarchical scan over [outc | inc] (40000 ints) ----------
__global__ __launch_bounds__(256) void scanA_kernel(const int* __restrict__ cnt,
                                                    int* __restrict__ partials)
{
    int b = blockIdx.x, t = threadIdx.x, lane = t & 63, w = t >> 6;
    int base = b * 1024 + t * 4;
    int s = 0;
#pragma unroll
    for (int i = 0; i < 4; ++i) {
        int idx = base + i;
        if (idx < 2 * NN) s += cnt[idx];
    }
#pragma unroll
    for (int off = 32; off > 0; off >>= 1) s += __shfl_down(s, off, 64);
    __shared__ int wsum[4];
    if (lane == 0) wsum[w] = s;
    __syncthreads();
    if (t == 0) partials[b] = wsum[0] + wsum[1] + wsum[2] + wsum[3];
}

__global__ __launch_bounds__(64) void scanB_kernel(const int* __restrict__ partials,
                                                   int* __restrict__ bases)
{
    int l = threadIdx.x;
    int p = (l < 40) ? partials[l] : 0;
    int v = p;
#pragma unroll
    for (int off = 1; off < 64; off <<= 1) {
        int u = __shfl_up(v, off, 64);
        if (l >= off) v += u;
    }
    if (l < 40) bases[l] = v - p;   // exclusive
}

__global__ __launch_bounds__(256) void scanC_kernel(const int* __restrict__ cnt,
                                                    const int* __restrict__ bases,
                                                    int* __restrict__ rps,
                                                    int* __restrict__ rpd,
                                                    float* __restrict__ invd)
{
    int b = blockIdx.x, t = threadIdx.x, lane = t & 63, w = t >> 6;
    int base = b * 1024 + t * 4;
    int v[4], s = 0;
#pragma unroll
    for (int i = 0; i < 4; ++i) {
        int idx = base + i;
        v[i] = (idx < 2 * NN) ? cnt[idx] : 0;
        s += v[i];
    }
    int tsum = s, sc = s;
#pragma unroll
    for (int off = 1; off < 64; off <<= 1) {
        int u = __shfl_up(sc, off, 64);
        if (lane >= off) sc += u;
    }
    __shared__ int wtot[4];
    if (lane == 63) wtot[w] = sc;
    __syncthreads();
    int wbase = 0;
    for (int j = 0; j < w; ++j) wbase += wtot[j];
    int run = bases[b] + wbase + sc - tsum;
#pragma unroll
    for (int i = 0; i < 4; ++i) {
        int idx = base + i;
        int e = run; run += v[i];
        if (idx < NN) {
            rps[idx] = e;
        } else if (idx < 2 * NN) {
            rpd[idx - NN] = e - NE;           // first-half total == NE
            invd[idx - NN] = 1.0f / fmaxf((float)v[i], 1.0f);
        }
    }
    if (b == 0 && t == 0) { rps[NN] = NE; rpd[NN] = NE; }
}

// ---------------- ek MLP into dst-CSR slots + src id per slot ----------------
__global__ __launch_bounds__(256) void ekfill_kernel(
    const int* __restrict__ ei, const float* __restrict__ ea,
    const float* __restrict__ k1w, const float* __restrict__ k1b,
    const int* __restrict__ rpd, int* __restrict__ fd,
    float* __restrict__ eks, int* __restrict__ smeta)
{
    int e = blockIdx.x * 256 + threadIdx.x;
    if (e >= NE) return;
    int s = ei[e], d = ei[NE + e];
    float a[6];
#pragma unroll
    for (int i = 0; i < 6; ++i) a[i] = ea[e * 6 + i];
    int slot_d = rpd[d] + atomicAdd(&fd[d], 1);
    smeta[slot_d] = s;                 // src node for this dst-CSR slot
#pragma unroll
    for (int j = 0; j < 16; ++j) {
        float v = k1b[j];
#pragma unroll
        for (int i = 0; i < 6; ++i) v = fmaf(a[i], k1w[i * 16 + j], v);
        eks[(size_t)slot_d * 16 + j] = fmaxf(v, 0.f);
    }
}

// ---------------- K2q[o][1088] / Rq[o][64] bf16 hi/lo (o-major for B-frags) --
__global__ __launch_bounds__(256) void gwt2_kernel(
    const float* __restrict__ k2w, const float* __restrict__ k2b,
    const float* __restrict__ rootw,
    unsigned short* __restrict__ K2qh, unsigned short* __restrict__ K2ql,
    unsigned short* __restrict__ Rqh, unsigned short* __restrict__ Rql)
{
    int idx = blockIdx.x * 256 + threadIdx.x;
    if (idx >= 64 * 1152) return;
    int o = idx / 1152, j = idx - o * 1152;
    float g;
    if (j < 1024)      { int c = j >> 6, k = j & 63; g = k2w[c * 4096 + k * 64 + o]; }
    else if (j < 1088) { int k = j - 1024;           g = k2b[k * 64 + o]; }
    else               { int k = j - 1088;           g = rootw[k * 64 + o]; }
    unsigned short hi = f2bf(g);
    unsigned short lo = f2bf(g - bf2f(hi));
    if (j < 1088) { K2qh[o * 1088 + j] = hi; K2ql[o * 1088 + j] = lo; }
    else { int k = j - 1088; Rqh[o * 64 + k] = hi; Rql[o * 64 + k] = lo; }
}

// ---------------- h0 = x*fc1_w + fc1_b -> f32 + hi/lo bf16 ----------------
__global__ __launch_bounds__(256) void h0_kernel(
    const float* __restrict__ x, const float* __restrict__ w,
    const float* __restrict__ b, float* __restrict__ h,
    unsigned short* __restrict__ hhi, unsigned short* __restrict__ hlo)
{
    int idx = blockIdx.x * 256 + threadIdx.x;
    if (idx >= NN * WD) return;
    int n = idx >> 6, o = idx & 63;
    float v = fmaf(x[n], w[o], b[o]);
    h[idx] = v;
    unsigned short hi = f2bf(v);
    hhi[idx] = hi;
    hlo[idx] = f2bf(v - bf2f(hi));
}

// ---------------- ucomp: U_i[c*64+k] = sum_e ek_e[c]*h[src_e][k]; strip16=sum h
// One wave per dst node. eks/smeta/h-index loads forced onto the VECTOR
// (TCP) path via to_vgpr: scalar K$ has too few MSHRs for a 6.4 MB eks
// stream (R15's ~33 us == MSHR-serialized). Same values, same FMA order.
__global__ __launch_bounds__(256) void ucomp_kernel(
    const float* __restrict__ h, const float* __restrict__ eks,
    const int* __restrict__ smeta, const int* __restrict__ rpd,
    unsigned short* __restrict__ Uhi, unsigned short* __restrict__ Ulo,
    int nbase, int nend)
{
    int wv = threadIdx.x >> 6;
    int i = nbase + blockIdx.x * 4 + wv;
    if (i >= nend) return;
    int l = threadIdx.x & 63;
    float acc[17];
#pragma unroll
    for (int c = 0; c < 17; ++c) acc[c] = 0.f;
    int r0 = rpd[i], r1 = rpd[i + 1];
    if (r0 < r1) {
        int su = to_vgpr(r0);
        float hv = h[(size_t)smeta[su] * 64 + l];
        const float* er = eks + (size_t)su * 16;
        f32x4 e0 = *(const f32x4*)(er);
        f32x4 e1 = *(const f32x4*)(er + 4);
        f32x4 e2 = *(const f32x4*)(er + 8);
        f32x4 e3 = *(const f32x4*)(er + 12);
        for (int s = r0; s < r1; ++s) {
            float ch = hv;
            f32x4 c0 = e0, c1 = e1, c2 = e2, c3 = e3;
            if (s + 1 < r1) {   // prefetch next edge during this edge's FMAs
                int s2 = to_vgpr(s + 1);
                hv = h[(size_t)smeta[s2] * 64 + l];
                const float* er2 = eks + (size_t)s2 * 16;
                e0 = *(const f32x4*)(er2);
                e1 = *(const f32x4*)(er2 + 4);
                e2 = *(const f32x4*)(er2 + 8);
                e3 = *(const f32x4*)(er2 + 12);
            }
            acc[0]  = fmaf(c0[0], ch, acc[0]);
            acc[1]  = fmaf(c0[1], ch, acc[1]);
            acc[2]  = fmaf(c0[2], ch, acc[2]);
            acc[3]  = fmaf(c0[3], ch, acc[3]);
            acc[4]  = fmaf(c1[0], ch, acc[4]);
            acc[5]  = fmaf(c1[1], ch, acc[5]);
            acc[6]  = fmaf(c1[2], ch, acc[6]);
            acc[7]  = fmaf(c1[3], ch, acc[7]);
            acc[8]  = fmaf(c2[0], ch, acc[8]);
            acc[9]  = fmaf(c2[1], ch, acc[9]);
            acc[10] = fmaf(c2[2], ch, acc[10]);
            acc[11] = fmaf(c2[3], ch, acc[11]);
            acc[12] = fmaf(c3[0], ch, acc[12]);
            acc[13] = fmaf(c3[1], ch, acc[13]);
            acc[14] = fmaf(c3[2], ch, acc[14]);
            acc[15] = fmaf(c3[3], ch, acc[15]);
            acc[16] += ch;
        }
    }
    size_t ub = (size_t)(i - nbase) * 1088 + l;
#pragma unroll
    for (int c = 0; c < 17; ++c) {
        unsigned short hi = f2bf(acc[c]);
        Uhi[ub + c * 64] = hi;
        Ulo[ub + c * 64] = f2bf(acc[c] - bf2f(hi));
    }
}

// ---------------- ugemm: h_out = relu((U @ K2q)*invd + h_in@rootw + convb) ---
// 16 rows/block (1250 blocks, ALL resident), 256 thr = 4 waves, wave w owns
// col-tile [w*16, w*16+16). Only A staged (4 KB/chunk, double-buffered via
// global_load_lds); B (K2q, 278 KB, L2-hot) read directly in the MFMA loop,
// latency hidden by ~20 resident waves/CU. Barrier drain per chunk = 4 KB.
__global__ __launch_bounds__(256, 6) void ugemm_kernel(
    const unsigned short* __restrict__ Uhi, const unsigned short* __restrict__ Ulo,
    const unsigned short* __restrict__ K2qh, const unsigned short* __restrict__ K2ql,
    const unsigned short* __restrict__ Rqh, const unsigned short* __restrict__ Rql,
    const unsigned short* __restrict__ hhi_in, const unsigned short* __restrict__ hlo_in,
    const float* __restrict__ invd, const float* __restrict__ convb,
    float* __restrict__ h_out, unsigned short* __restrict__ hhi_out,
    unsigned short* __restrict__ hlo_out, int nbase, int nend)
{
    __shared__ __align__(16) unsigned short Asm[2][8][2][16][8];  // 2 x 4 KB
    int tid = threadIdx.x;
    int w = tid >> 6, l = tid & 63;
    int quad = l >> 4, lr = l & 15;
    int n0 = nbase + blockIdx.x * 16;
    int n0l = n0 - nbase;
    int ncl = nend - nbase;

    // staging unit u = tid: LDS offset tid*16 (wave-uniform base + lane*16);
    // source = (half ? Ulo : Uhi)[row rla][k-octet ga], advances 64/chunk.
    int ga = tid >> 5, ha = (tid >> 4) & 1, ra = tid & 15;
    int rla = n0l + ra; if (rla >= ncl) rla = ncl - 1;
    const unsigned short* asrc = (ha ? Ulo : Uhi) + (size_t)rla * 1088 + ga * 8;

    gl_lds16(asrc, (void*)&Asm[0][ga][ha][ra][0]);   // prologue: chunk 0
    __syncthreads();

    int o = w * 16 + lr;
    const unsigned short* pbh = K2qh + (size_t)o * 1088 + quad * 8;
    const unsigned short* pbl = K2ql + (size_t)o * 1088 + quad * 8;
    f32x4 acc = {0.f, 0.f, 0.f, 0.f};
    int cur = 0;
    for (int c = 0; c < 17; ++c) {
        if (c + 1 < 17)
            gl_lds16(asrc + (size_t)(c + 1) * 64,
                     (void*)&Asm[cur ^ 1][ga][ha][ra][0]);
        int kb = c * 64;
#pragma unroll
        for (int kk = 0; kk < 2; ++kk) {
            int g = kk * 4 + quad;
            bf16x8 ah = *(const bf16x8*)&Asm[cur][g][0][lr][0];
            bf16x8 av = *(const bf16x8*)&Asm[cur][g][1][lr][0];
            bf16x8 bh = *(const bf16x8*)(pbh + kb + kk * 32);
            bf16x8 bl = *(const bf16x8*)(pbl + kb + kk * 32);
            acc = __builtin_amdgcn_mfma_f32_16x16x32_bf16(ah, bh, acc, 0, 0, 0);
            acc = __builtin_amdgcn_mfma_f32_16x16x32_bf16(ah, bl, acc, 0, 0, 0);
            acc = __builtin_amdgcn_mfma_f32_16x16x32_bf16(av, bh, acc, 0, 0, 0);
        }
        __syncthreads();        // drains staging vmcnt; publishes buf^1
        cur ^= 1;
    }

    // root term: h_in @ rootw (NOT divided by deg)
    int row = n0 + lr;
    if (row > nend - 1) row = nend - 1;
    f32x4 r0a = {0.f, 0.f, 0.f, 0.f};
    const unsigned short* prh = hhi_in + (size_t)row * 64 + quad * 8;
    const unsigned short* prl = hlo_in + (size_t)row * 64 + quad * 8;
#pragma unroll
    for (int ks = 0; ks < 2; ++ks) {
        bf16x8 ah = *(const bf16x8*)(prh + ks * 32);
        bf16x8 av = *(const bf16x8*)(prl + ks * 32);
        bf16x8 bh = *(const bf16x8*)(Rqh + (size_t)o * 64 + ks * 32 + quad * 8);
        bf16x8 bl = *(const bf16x8*)(Rql + (size_t)o * 64 + ks * 32 + quad * 8);
        r0a = __builtin_amdgcn_mfma_f32_16x16x32_bf16(ah, bh, r0a, 0, 0, 0);
        r0a = __builtin_amdgcn_mfma_f32_16x16x32_bf16(ah, bl, r0a, 0, 0, 0);
        r0a = __builtin_amdgcn_mfma_f32_16x16x32_bf16(av, bh, r0a, 0, 0, 0);
    }
    float cb0 = convb[o];
    // C/D layout: col = lane&15 (-> o), row = quad*4 + rr
#pragma unroll
    for (int rr = 0; rr < 4; ++rr) {
        int gn = n0 + quad * 4 + rr;
        if (gn < nend) {
            float iv = invd[gn];
            size_t idx0 = (size_t)gn * 64 + o;
            float v0 = fmaf(acc[rr], iv, r0a[rr] + cb0);
            v0 = fmaxf(v0, 0.f);
            h_out[idx0] = v0;
            unsigned short x0 = f2bf(v0);
            hhi_out[idx0] = x0;
            hlo_out[idx0] = f2bf(v0 - bf2f(x0));
        }
    }
}

// ---------------- out = h @ fc2_w + fc2_b ----------------
__global__ __launch_bounds__(256) void out_kernel(
    const float* __restrict__ h, const float* __restrict__ fc2_w,
    const float* __restrict__ fc2_b, float* __restrict__ out)
{
    int wave = blockIdx.x * 4 + (threadIdx.x >> 6);
    int lane = threadIdx.x & 63;
    float v = h[(size_t)wave * 64 + lane] * fc2_w[lane];
#pragma unroll
    for (int off = 32; off > 0; off >>= 1) v += __shfl_down(v, off);
    if (lane == 0) out[wave] = v + fc2_b[0];
}

extern "C" void kernel_launch(void* const* d_in, const int* in_sizes, int n_in,
                              void* d_out, int out_size, void* d_ws, size_t ws_size,
                              hipStream_t stream)
{
    const float* x         = (const float*)d_in[0];
    const int*   ei        = (const int*)  d_in[1];
    const float* edge_attr = (const float*)d_in[2];
    const float* fc1_w     = (const float*)d_in[3];
    const float* fc1_b     = (const float*)d_in[4];
    const float* k1_w      = (const float*)d_in[5];
    const float* k1_b      = (const float*)d_in[6];
    const float* k2_w      = (const float*)d_in[7];
    const float* k2_b      = (const float*)d_in[8];
    const float* root_w    = (const float*)d_in[9];
    const float* conv_b    = (const float*)d_in[10];
    const float* fc2_w     = (const float*)d_in[11];
    const float* fc2_b     = (const float*)d_in[12];
    float* out = (float*)d_out;

    // workspace layout, f32 units (all chunk sizes multiples of 4 -> 16B align)
    float* ws = (float*)d_ws;
    size_t off = 0;
    int* cnt   = (int*)(ws + off); off += 4 * NN;       // outc|inc|fs|fd
    int* outc  = cnt;
    int* inc   = cnt + NN;
    int* fd    = cnt + 3 * NN;
    int* rps   = (int*)(ws + off); off += 20004;
    int* rpd   = (int*)(ws + off); off += 20004;
    int* partials = (int*)(ws + off); off += 64;
    int* bases    = (int*)(ws + off); off += 64;
    int* smeta    = (int*)(ws + off); off += NE + 16;   // src node per dst-slot
    float* invd  = ws + off; off += NN;
    float* eks   = ws + off; off += (size_t)NE * 16;
    unsigned short* K2qh = (unsigned short*)(ws + off); off += 34816;  // 64x1088
    unsigned short* K2ql = (unsigned short*)(ws + off); off += 34816;
    unsigned short* Rqh  = (unsigned short*)(ws + off); off += 2048;   // 64x64
    unsigned short* Rql  = (unsigned short*)(ws + off); off += 2048;
    float* hA    = ws + off; off += (size_t)NN * WD;
    float* hB    = ws + off; off += (size_t)NN * WD;
    unsigned short* hhiA = (unsigned short*)(ws + off); off += (size_t)NN * 32;
    unsigned short* hloA = (unsigned short*)(ws + off); off += (size_t)NN * 32;
    unsigned short* hhiB = (unsigned short*)(ws + off); off += (size_t)NN * 32;
    unsigned short* hloB = (unsigned short*)(ws + off); off += (size_t)NN * 32;

    // U chunking (bf16 hi/lo planes, csz*1088 f32 units total)
    size_t totalf = ws_size / sizeof(float);
    size_t availf = totalf > off ? totalf - off : 0;
    const int divs[] = {1, 2, 4, 5, 8, 10, 20};
    int nch = 20;
    for (int di = 0; di < 7; ++di) {
        if (availf >= (size_t)(NN / divs[di]) * 1088) { nch = divs[di]; break; }
    }
    int csz = NN / nch;
    unsigned short* Uhi = (unsigned short*)(ws + off);
    unsigned short* Ulo = (unsigned short*)(ws + off + (size_t)csz * 544);

    hipMemsetAsync(cnt, 0, 4 * NN * sizeof(int), stream);
    count_kernel<<<(NE + 255) / 256, 256, 0, stream>>>(ei, outc, inc);
    scanA_kernel<<<40, 256, 0, stream>>>(cnt, partials);
    scanB_kernel<<<1, 64, 0, stream>>>(partials, bases);
    scanC_kernel<<<40, 256, 0, stream>>>(cnt, bases, rps, rpd, invd);
    ekfill_kernel<<<(NE + 255) / 256, 256, 0, stream>>>(ei, edge_attr, k1_w, k1_b,
                                                        rpd, fd, eks, smeta);
    gwt2_kernel<<<(64 * 1152 + 255) / 256, 256, 0, stream>>>(k2_w, k2_b, root_w,
                                                             K2qh, K2ql, Rqh, Rql);
    h0_kernel<<<(NN * WD + 255) / 256, 256, 0, stream>>>(x, fc1_w, fc1_b,
                                                         hA, hhiA, hloA);

    const float* hin = hA; float* hout = hB;
    const unsigned short* hhin = hhiA; const unsigned short* hloin = hloA;
    unsigned short* hhout = hhiB; unsigned short* hloout = hloB;
    for (int layer = 0; layer < DEPTH; ++layer) {
        for (int c = 0; c < nch; ++c) {
            int nb = c * csz, ne2 = nb + csz;
            ucomp_kernel<<<(csz + 3) / 4, 256, 0, stream>>>(
                hin, eks, smeta, rpd, Uhi, Ulo, nb, ne2);
            ugemm_kernel<<<(csz + 15) / 16, 256, 0, stream>>>(
                Uhi, Ulo, K2qh, K2ql, Rqh, Rql, hhin, hloin, invd, conv_b,
                hout, hhout, hloout, nb, ne2);
        }
        const float* t0 = hin; hin = hout; hout = (float*)t0;
        const unsigned short* t1 = hhin; hhin = hhout; hhout = (unsigned short*)t1;
        const unsigned short* t2 = hloin; hloin = hloout; hloout = (unsigned short*)t2;
    }

    out_kernel<<<NN / 4, 256, 0, stream>>>(hin, fc2_w, fc2_b, out);
}